// Round 1
// baseline (914.711 us; speedup 1.0000x reference)
//
#include <hip/hip_runtime.h>
#include <hip/hip_bf16.h>
#include <cmath>

typedef __bf16 bf16_t;
typedef bf16_t bf16x8 __attribute__((ext_vector_type(8)));
typedef float f32x4 __attribute__((ext_vector_type(4)));

#define LDK 40   // 32 + 8 bf16 pad (16B) -> 80B row stride, 16B aligned, 2-way bank alias (free)

__device__ __forceinline__ f32x4 zero4(){ f32x4 z; z[0]=0.f; z[1]=0.f; z[2]=0.f; z[3]=0.f; return z; }

__device__ __forceinline__ bf16x8 cvt8(float4 a, float4 b){
  bf16x8 r;
  r[0]=(bf16_t)a.x; r[1]=(bf16_t)a.y; r[2]=(bf16_t)a.z; r[3]=(bf16_t)a.w;
  r[4]=(bf16_t)b.x; r[5]=(bf16_t)b.y; r[6]=(bf16_t)b.z; r[7]=(bf16_t)b.w;
  return r;
}

__device__ __forceinline__ float gelu_tanh_f(float x){
  float x3 = x*x*x;
  return 0.5f*x*(1.0f + tanhf(0.7978845608028654f*(x + 0.044715f*x3)));
}

// ---------------- GEMM: C[M,N] = A[M,K] * W[N,K]^T (+bias)(+resid)(+gelu) ----------------
template<int BM, int GELU>
__device__ __forceinline__ void gemm_body(
    const float* __restrict__ A, const float* __restrict__ W,
    const float* __restrict__ bias, const float* __restrict__ resid,
    float* __restrict__ C, int M, int N, int K,
    int kt0, int ktn, int brow, int bcol)
{
  constexpr int IA = BM/64;          // A staging segs per thread (seg = 8 f32)
  constexpr int WR = BM/2;           // rows per wave
  constexpr int MF = BM/32;          // 16-row frags per wave
  __shared__ __attribute__((aligned(16))) bf16_t As[2][BM][LDK];
  __shared__ __attribute__((aligned(16))) bf16_t Bs[2][128][LDK];

  const int tid  = threadIdx.x;
  const int lane = tid & 63;
  const int wave = tid >> 6;
  const int wr = wave >> 1, wc = wave & 1;

  float4 ga[2*IA], gb[4];

  auto load_g = [&](int kt){
    #pragma unroll
    for (int i=0;i<IA;i++){
      int s = tid + i*256; int row = s>>2; int k0 = (s&3)*8;
      const float4* p = reinterpret_cast<const float4*>(A + (size_t)(brow+row)*K + (size_t)kt*32 + k0);
      ga[2*i] = p[0]; ga[2*i+1] = p[1];
    }
    #pragma unroll
    for (int i=0;i<2;i++){
      int s = tid + i*256; int row = s>>2; int k0 = (s&3)*8;
      const float4* p = reinterpret_cast<const float4*>(W + (size_t)(bcol+row)*K + (size_t)kt*32 + k0);
      gb[2*i] = p[0]; gb[2*i+1] = p[1];
    }
  };
  auto write_l = [&](int buf){
    #pragma unroll
    for (int i=0;i<IA;i++){
      int s = tid + i*256; int row = s>>2; int k0 = (s&3)*8;
      *reinterpret_cast<bf16x8*>(&As[buf][row][k0]) = cvt8(ga[2*i], ga[2*i+1]);
    }
    #pragma unroll
    for (int i=0;i<2;i++){
      int s = tid + i*256; int row = s>>2; int k0 = (s&3)*8;
      *reinterpret_cast<bf16x8*>(&Bs[buf][row][k0]) = cvt8(gb[2*i], gb[2*i+1]);
    }
  };

  f32x4 acc[MF][4];
  #pragma unroll
  for (int m=0;m<MF;m++)
    #pragma unroll
    for (int n=0;n<4;n++) acc[m][n] = zero4();

  load_g(kt0);
  write_l(0);
  __syncthreads();

  for (int t=0; t<ktn; ++t){
    const int cur = t & 1;
    if (t+1 < ktn) load_g(kt0 + t + 1);      // issue next-tile global loads early (T14)
    bf16x8 af[MF], bfr[4];
    #pragma unroll
    for (int m=0;m<MF;m++)
      af[m] = *reinterpret_cast<const bf16x8*>(&As[cur][wr*WR + m*16 + (lane&15)][(lane>>4)*8]);
    #pragma unroll
    for (int n=0;n<4;n++)
      bfr[n] = *reinterpret_cast<const bf16x8*>(&Bs[cur][wc*64 + n*16 + (lane&15)][(lane>>4)*8]);
    #pragma unroll
    for (int m=0;m<MF;m++)
      #pragma unroll
      for (int n=0;n<4;n++)
        acc[m][n] = __builtin_amdgcn_mfma_f32_16x16x32_bf16(af[m], bfr[n], acc[m][n], 0,0,0);
    if (t+1 < ktn) write_l(cur ^ 1);
    __syncthreads();
  }

  #pragma unroll
  for (int m=0;m<MF;m++){
    #pragma unroll
    for (int n=0;n<4;n++){
      const int gn = bcol + wc*64 + n*16 + (lane&15);
      const float bv = bias ? bias[gn] : 0.f;
      #pragma unroll
      for (int r=0;r<4;r++){
        const int gm = brow + wr*WR + m*16 + (lane>>4)*4 + r;
        float v = acc[m][n][r] + bv;
        if (resid) v += resid[(size_t)gm*N + gn];
        if (GELU)  v = gelu_tanh_f(v);
        C[(size_t)gm*N + gn] = v;
      }
    }
  }
}

template<int BM, int GELU>
__global__ __launch_bounds__(256,2) void gemm_kernel(
    const float* __restrict__ A, const float* __restrict__ W,
    const float* __restrict__ bias, const float* __restrict__ resid,
    float* __restrict__ C, int M, int N, int K)
{
  const int KT  = K >> 5;
  const int nz  = gridDim.z;
  const int ktn = KT / nz;
  const int z   = blockIdx.z;
  const float* bias_e  = (z==0) ? bias  : nullptr;
  const float* resid_e = (z==0) ? resid : nullptr;
  float* C_e = C + (size_t)z * (size_t)M * (size_t)N;   // partial z lands in the next scratch buffer
  gemm_body<BM,GELU>(A, W, bias_e, resid_e, C_e, M, N, K, z*ktn, ktn, blockIdx.x*BM, blockIdx.y*128);
}

// fused Q/K/V: one launch, blockIdx.y in [0,96) spans three 4096-wide outputs
__global__ __launch_bounds__(256,2) void gemm_qkv_kernel(
    const float* __restrict__ A,
    const float* __restrict__ W0, const float* __restrict__ W1, const float* __restrict__ W2,
    const float* __restrict__ b0, const float* __restrict__ b1, const float* __restrict__ b2,
    float* __restrict__ C0, float* __restrict__ C1, float* __restrict__ C2, int K)
{
  const int gcol = blockIdx.y * 128;
  const int which = gcol >> 12;
  const float* W    = (which==0) ? W0 : ((which==1) ? W1 : W2);
  const float* bias = (which==0) ? b0 : ((which==1) ? b1 : b2);
  float* C          = (which==0) ? C0 : ((which==1) ? C1 : C2);
  gemm_body<64,0>(A, W, bias, nullptr, C, 512, 4096, K, 0, K>>5, blockIdx.x*64, gcol & 4095);
}

// ---------------- flash attention: grid (4 qblocks, 64 heads), 256 thr ----------------
__global__ __launch_bounds__(256) void attn_kernel(
    const float* __restrict__ q, const float* __restrict__ k,
    const float* __restrict__ v, float* __restrict__ ctx)
{
  constexpr int HID = 4096;
  const int qblk = blockIdx.x, head = blockIdx.y;
  const int tid = threadIdx.x, lane = tid & 63, wave = tid >> 6;

  __shared__ __attribute__((aligned(16))) bf16_t Ks[128][72];
  __shared__ __attribute__((aligned(16))) bf16_t Vt[64][136];
  __shared__ __attribute__((aligned(16))) bf16_t Ps[4][32][136];

  // Q fragments held in registers for the whole kernel
  bf16x8 qf[2][2];
  const int qrow0 = qblk*128 + wave*32;
  #pragma unroll
  for (int m=0;m<2;m++)
    #pragma unroll
    for (int ks=0;ks<2;ks++){
      const float4* p = reinterpret_cast<const float4*>(
          q + (size_t)(qrow0 + m*16 + (lane&15))*HID + head*64 + ks*32 + (lane>>4)*8);
      qf[m][ks] = cvt8(p[0], p[1]);
    }

  f32x4 o[2][4];
  float mrow[2][4], lrow[2][4];
  #pragma unroll
  for (int m=0;m<2;m++){
    #pragma unroll
    for (int n=0;n<4;n++) o[m][n] = zero4();
    #pragma unroll
    for (int r=0;r<4;r++){ mrow[m][r] = -1e30f; lrow[m][r] = 0.f; }
  }

  for (int t=0; t<4; ++t){
    __syncthreads();                      // previous tile's reads done before restage
    #pragma unroll
    for (int i=0;i<4;i++){                // stage K tile [128][64]
      int s = tid + i*256; int row = s>>3; int c0 = (s&7)*8;
      const float4* p = reinterpret_cast<const float4*>(k + (size_t)(t*128+row)*HID + head*64 + c0);
      *reinterpret_cast<bf16x8*>(&Ks[row][c0]) = cvt8(p[0], p[1]);
    }
    #pragma unroll
    for (int i=0;i<4;i++){                // stage V transposed [64][128]
      int s = tid + i*256; int row = s>>3; int c0 = (s&7)*8;
      const float4* p = reinterpret_cast<const float4*>(v + (size_t)(t*128+row)*HID + head*64 + c0);
      float4 f0 = p[0], f1 = p[1];
      Vt[c0+0][row]=(bf16_t)f0.x; Vt[c0+1][row]=(bf16_t)f0.y;
      Vt[c0+2][row]=(bf16_t)f0.z; Vt[c0+3][row]=(bf16_t)f0.w;
      Vt[c0+4][row]=(bf16_t)f1.x; Vt[c0+5][row]=(bf16_t)f1.y;
      Vt[c0+6][row]=(bf16_t)f1.z; Vt[c0+7][row]=(bf16_t)f1.w;
    }
    __syncthreads();

    // S = Q K^T   (32 q-rows per wave x 128 kv)
    f32x4 sa[2][8];
    #pragma unroll
    for (int m=0;m<2;m++)
      #pragma unroll
      for (int n=0;n<8;n++) sa[m][n] = zero4();
    #pragma unroll
    for (int ks=0;ks<2;ks++){
      #pragma unroll
      for (int n=0;n<8;n++){
        bf16x8 kf = *reinterpret_cast<const bf16x8*>(&Ks[n*16 + (lane&15)][ks*32 + (lane>>4)*8]);
        sa[0][n] = __builtin_amdgcn_mfma_f32_16x16x32_bf16(qf[0][ks], kf, sa[0][n], 0,0,0);
        sa[1][n] = __builtin_amdgcn_mfma_f32_16x16x32_bf16(qf[1][ks], kf, sa[1][n], 0,0,0);
      }
    }

    // online softmax; write P (bf16) to per-wave LDS for re-layout
    #pragma unroll
    for (int m=0;m<2;m++){
      float pm[4], rs[4];
      #pragma unroll
      for (int r=0;r<4;r++){
        float mx = sa[m][0][r];
        #pragma unroll
        for (int n=1;n<8;n++) mx = fmaxf(mx, sa[m][n][r]);
        pm[r] = mx * 0.125f;
        #pragma unroll
        for (int off=1; off<16; off<<=1) pm[r] = fmaxf(pm[r], __shfl_xor(pm[r], off));
        float mnew  = fmaxf(mrow[m][r], pm[r]);
        float alpha = __expf(mrow[m][r] - mnew);
        mrow[m][r] = mnew; lrow[m][r] *= alpha;
        #pragma unroll
        for (int n=0;n<4;n++) o[m][n][r] *= alpha;
        rs[r] = 0.f;
      }
      #pragma unroll
      for (int n=0;n<8;n++)
        #pragma unroll
        for (int r=0;r<4;r++){
          float p = __expf(sa[m][n][r]*0.125f - mrow[m][r]);
          rs[r] += p;
          Ps[wave][m*16 + (lane>>4)*4 + r][n*16 + (lane&15)] = (bf16_t)p;
        }
      #pragma unroll
      for (int r=0;r<4;r++){
        #pragma unroll
        for (int off=1; off<16; off<<=1) rs[r] += __shfl_xor(rs[r], off);
        lrow[m][r] += rs[r];
      }
    }

    // PV: o += P[32x128] * V[128x64]   (Ps is per-wave; no barrier needed)
    #pragma unroll
    for (int ksv=0;ksv<4;ksv++){
      bf16x8 pf[2], vf[4];
      #pragma unroll
      for (int m=0;m<2;m++)
        pf[m] = *reinterpret_cast<const bf16x8*>(&Ps[wave][m*16 + (lane&15)][ksv*32 + (lane>>4)*8]);
      #pragma unroll
      for (int n=0;n<4;n++)
        vf[n] = *reinterpret_cast<const bf16x8*>(&Vt[n*16 + (lane&15)][ksv*32 + (lane>>4)*8]);
      #pragma unroll
      for (int m=0;m<2;m++)
        #pragma unroll
        for (int n=0;n<4;n++)
          o[m][n] = __builtin_amdgcn_mfma_f32_16x16x32_bf16(pf[m], vf[n], o[m][n], 0,0,0);
    }
  }

  #pragma unroll
  for (int m=0;m<2;m++)
    #pragma unroll
    for (int n=0;n<4;n++)
      #pragma unroll
      for (int r=0;r<4;r++){
        const int gm = qrow0 + m*16 + (lane>>4)*4 + r;
        const int gd = head*64 + n*16 + (lane&15);
        ctx[(size_t)gm*HID + gd] = o[m][n][r] / lrow[m][r];
      }
}

// ---------------- LayerNorm over 4096 (x0 [+ x1]) ----------------
__global__ __launch_bounds__(256) void ln4096_kernel(
    const float* __restrict__ x0, const float* __restrict__ x1,
    const float* __restrict__ g, const float* __restrict__ b,
    float* __restrict__ y)
{
  __shared__ float red[4];
  const int row = blockIdx.x, tid = threadIdx.x;
  const size_t base = (size_t)row * 4096;
  float vals[16];
  float s = 0.f;
  #pragma unroll
  for (int i=0;i<16;i++){
    int c = i*256 + tid;
    float t = x0[base+c];
    if (x1) t += x1[base+c];
    vals[i] = t; s += t;
  }
  #pragma unroll
  for (int off=1; off<64; off<<=1) s += __shfl_xor(s, off);
  if (!(tid&63)) red[tid>>6] = s;
  __syncthreads();
  const float mean = (red[0]+red[1]+red[2]+red[3]) * (1.0f/4096.0f);
  __syncthreads();
  float s2 = 0.f;
  #pragma unroll
  for (int i=0;i<16;i++){ float d = vals[i]-mean; s2 += d*d; }
  #pragma unroll
  for (int off=1; off<64; off<<=1) s2 += __shfl_xor(s2, off);
  if (!(tid&63)) red[tid>>6] = s2;
  __syncthreads();
  const float rstd = rsqrtf((red[0]+red[1]+red[2]+red[3])*(1.0f/4096.0f) + 1e-12f);
  #pragma unroll
  for (int i=0;i<16;i++){
    int c = i*256 + tid;
    y[base+c] = (vals[i]-mean)*rstd*g[c] + b[c];
  }
}

// ---------------- embeddings + LayerNorm(128) ----------------
__global__ __launch_bounds__(128) void embed_ln_kernel(
    const float* __restrict__ we, const float* __restrict__ te, const float* __restrict__ pe,
    const float* __restrict__ g, const float* __restrict__ bb,
    const int* __restrict__ ids, const int* __restrict__ tt, const int* __restrict__ pos,
    float* __restrict__ out)
{
  __shared__ float red[2];
  const int row = blockIdx.x, tid = threadIdx.x;
  float e = we[(size_t)ids[row]*128 + tid] + te[(size_t)tt[row]*128 + tid] + pe[(size_t)pos[row]*128 + tid];
  float s = e;
  #pragma unroll
  for (int off=1; off<64; off<<=1) s += __shfl_xor(s, off);
  if (!(tid&63)) red[tid>>6] = s;
  __syncthreads();
  const float mean = (red[0]+red[1]) * (1.0f/128.0f);
  __syncthreads();
  float d = e - mean;
  float s2 = d*d;
  #pragma unroll
  for (int off=1; off<64; off<<=1) s2 += __shfl_xor(s2, off);
  if (!(tid&63)) red[tid>>6] = s2;
  __syncthreads();
  const float var = (red[0]+red[1]) * (1.0f/128.0f);
  out[(size_t)row*128 + tid] = d * rsqrtf(var + 1e-12f) * g[tid] + bb[tid];
}

// ---------------- launch ----------------
extern "C" void kernel_launch(void* const* d_in, const int* in_sizes, int n_in,
                              void* d_out, int out_size, void* d_ws, size_t ws_size,
                              hipStream_t stream) {
  const float* we   = (const float*)d_in[0];
  const float* te   = (const float*)d_in[1];
  const float* pe   = (const float*)d_in[2];
  const float* ln0g = (const float*)d_in[3];
  const float* ln0b = (const float*)d_in[4];
  const float* Wp   = (const float*)d_in[5];
  const float* bp   = (const float*)d_in[6];
  const float* Wq   = (const float*)d_in[7];
  const float* bq   = (const float*)d_in[8];
  const float* Wk   = (const float*)d_in[9];
  const float* bk   = (const float*)d_in[10];
  const float* Wv   = (const float*)d_in[11];
  const float* bv   = (const float*)d_in[12];
  const float* Wo   = (const float*)d_in[13];
  const float* bo   = (const float*)d_in[14];
  const float* ln1g = (const float*)d_in[15];
  const float* ln1b = (const float*)d_in[16];
  const float* Wf1  = (const float*)d_in[17];
  const float* bf1  = (const float*)d_in[18];
  const float* Wf2  = (const float*)d_in[19];
  const float* bf2  = (const float*)d_in[20];
  const float* ln2g = (const float*)d_in[21];
  const float* ln2b = (const float*)d_in[22];
  const int* ids = (const int*)d_in[23];
  const int* tt  = (const int*)d_in[24];
  const int* pos = (const int*)d_in[25];
  float* out = (float*)d_out;

  float* ws = (float*)d_ws;
  const size_t MN = (size_t)512*4096;
  float* h_e    = ws;                 // 512*128
  float* hidden = h_e + 512*128;      // MN
  float* qb     = hidden + MN;        // MN  (later: attn partial0 / ffn2 partial0)
  float* kb     = qb + MN;            // MN  (later: partial1 region = qb + MN, contiguous)
  float* vbuf   = kb + MN;            // MN  (later: h1)
  float* ctxb   = vbuf + MN;          // MN
  float* gelub  = ctxb + MN;          // 512*16384

  // embeddings + LN0
  embed_ln_kernel<<<dim3(512),dim3(128),0,stream>>>(we,te,pe,ln0g,ln0b,ids,tt,pos,h_e);
  // hidden = h_e @ Wp^T + bp   [512,4096], K=128
  gemm_kernel<64,0><<<dim3(8,32,1),dim3(256),0,stream>>>(h_e, Wp, bp, nullptr, hidden, 512, 4096, 128);
  // q,k,v fused
  gemm_qkv_kernel<<<dim3(8,96,1),dim3(256),0,stream>>>(hidden, Wq,Wk,Wv, bq,bk,bv, qb,kb,vbuf, 4096);
  // attention -> ctx
  attn_kernel<<<dim3(4,64),dim3(256),0,stream>>>(qb, kb, vbuf, ctxb);
  // attn_out = ctx @ Wo^T + bo + hidden ; split-K=2 (z=1 partial lands in kb region)
  gemm_kernel<64,0><<<dim3(8,32,2),dim3(256),0,stream>>>(ctxb, Wo, bo, hidden, qb, 512, 4096, 4096);
  // h1 = LN(qb + kb) -> vbuf
  ln4096_kernel<<<dim3(512),dim3(256),0,stream>>>(qb, kb, ln1g, ln1b, vbuf);
  // gelu(h1 @ Wf1^T + bf1) -> gelub   [512,16384]
  gemm_kernel<128,1><<<dim3(4,128,1),dim3(256),0,stream>>>(vbuf, Wf1, bf1, nullptr, gelub, 512, 16384, 4096);
  // ff2 = gelub @ Wf2^T + bf2 + h1 ; split-K=2 (z=1 partial -> kb region)
  gemm_kernel<64,0><<<dim3(8,32,2),dim3(256),0,stream>>>(gelub, Wf2, bf2, vbuf, qb, 512, 4096, 16384);
  // h2 = LN(qb + kb) -> out
  ln4096_kernel<<<dim3(512),dim3(256),0,stream>>>(qb, kb, ln2g, ln2b, out);
}

// Round 2
// 674.198 us; speedup vs baseline: 1.3567x; 1.3567x over previous
//
#include <hip/hip_runtime.h>
#include <hip/hip_bf16.h>
#include <cmath>

typedef __bf16 bf16_t;
typedef bf16_t bf16x8 __attribute__((ext_vector_type(8)));
typedef float f32x4 __attribute__((ext_vector_type(4)));

__device__ __forceinline__ f32x4 zero4(){ f32x4 z; z[0]=0.f; z[1]=0.f; z[2]=0.f; z[3]=0.f; return z; }

__device__ __forceinline__ bf16x8 cvt8(float4 a, float4 b){
  bf16x8 r;
  r[0]=(bf16_t)a.x; r[1]=(bf16_t)a.y; r[2]=(bf16_t)a.z; r[3]=(bf16_t)a.w;
  r[4]=(bf16_t)b.x; r[5]=(bf16_t)b.y; r[6]=(bf16_t)b.z; r[7]=(bf16_t)b.w;
  return r;
}

__device__ __forceinline__ float gelu_tanh_f(float x){
  float x3 = x*x*x;
  return 0.5f*x*(1.0f + tanhf(0.7978845608028654f*(x + 0.044715f*x3)));
}

// chunk swizzle for bf16 A-operands: 16B chunk c within each 32-elem K-tile, XOR'd by (row>>1)&3
__device__ __forceinline__ int swz_col(int row, int col){
  return (col & ~31) | (((((col>>3)&3) ^ ((row>>1)&3)))<<3) | (col&7);
}

#if defined(__has_builtin)
#if __has_builtin(__builtin_amdgcn_global_load_lds)
#define HAS_GLDS 1
#endif
#endif

__device__ __forceinline__ void async_cp16(const bf16_t* g, bf16_t* l){
#ifdef HAS_GLDS
  __builtin_amdgcn_global_load_lds(
      (const __attribute__((address_space(1))) unsigned int*)g,
      (__attribute__((address_space(3))) unsigned int*)l, 16, 0, 0);
#else
  // fallback: synchronous reg copy (per-lane l + lane offset handled by caller layout)
  ((bf16x8*)l)[threadIdx.x & 63] = ((const bf16x8*)g)[0];
#endif
}

// ============ GEMM: C[512,N] = A_bf16swz[512,K] * W_f32[N,K]^T ============
// EPI bits: 1 = store fp32 linear, 2 = store bf16 linear, 4 = store bf16 swizzled, 8 = gelu
template<int EPI>
__device__ __forceinline__ void gemm512_body(
    const bf16_t* __restrict__ A, const float* __restrict__ W,
    const float* __restrict__ bias,
    float* __restrict__ Cf, bf16_t* __restrict__ Cb,
    int Nc, int K, int kt0, int ktn, int ccol0)
{
  __shared__ __align__(16) bf16_t As[2][512*32];   // linear [512][32]
  __shared__ __align__(16) bf16_t Bs[2][64*40];    // [64][40] padded

  const int tid  = threadIdx.x;
  const int lane = tid & 63;
  const int wave = tid >> 6;

  auto stageA = [&](int buf, int kt){
    const bf16_t* s = A + (size_t)(tid>>2)*K + kt*32 + (tid&3)*8;
#ifdef HAS_GLDS
    bf16_t* dwave = &As[buf][(tid>>6)*512];
    #pragma unroll
    for (int j=0;j<8;j++)
      async_cp16(s + (size_t)j*64*K, dwave + j*2048);
#else
    #pragma unroll
    for (int j=0;j<8;j++)
      *(bf16x8*)&As[buf][j*2048 + tid*8] = *(const bf16x8*)(s + (size_t)j*64*K);
#endif
  };

  float4 gb0, gb1;
  auto loadB = [&](int kt){
    const float* p = W + (size_t)(tid>>2)*K + kt*32 + (tid&3)*8;
    gb0 = *(const float4*)p; gb1 = *(const float4*)(p+4);
  };
  auto writeB = [&](int buf){
    *(bf16x8*)&Bs[buf][(tid>>2)*40 + (tid&3)*8] = cvt8(gb0, gb1);
  };

  f32x4 acc[8][4];
  #pragma unroll
  for (int m=0;m<8;m++)
    #pragma unroll
    for (int n=0;n<4;n++) acc[m][n] = zero4();

  stageA(0, kt0);
  loadB(kt0);
  writeB(0);
  __syncthreads();

  for (int t=0; t<ktn; ++t){
    const int cur = t & 1;
    if (t+1 < ktn){ stageA(cur^1, kt0+t+1); loadB(kt0+t+1); }
    bf16x8 af[8], bfr[4];
    #pragma unroll
    for (int m=0;m<8;m++){
      const int R = wave*128 + m*16 + (lane&15);
      const int c = (lane>>4) ^ ((R>>1)&3);
      af[m] = *(const bf16x8*)&As[cur][R*32 + c*8];
    }
    #pragma unroll
    for (int n=0;n<4;n++)
      bfr[n] = *(const bf16x8*)&Bs[cur][(n*16 + (lane&15))*40 + (lane>>4)*8];
    #pragma unroll
    for (int m=0;m<8;m++)
      #pragma unroll
      for (int n=0;n<4;n++)
        acc[m][n] = __builtin_amdgcn_mfma_f32_16x16x32_bf16(af[m], bfr[n], acc[m][n], 0,0,0);
    if (t+1 < ktn) writeB(cur^1);
    __syncthreads();
  }

  #pragma unroll
  for (int m=0;m<8;m++){
    #pragma unroll
    for (int n=0;n<4;n++){
      const int col = n*16 + (lane&15);
      const float bv = bias ? bias[col] : 0.f;
      #pragma unroll
      for (int r=0;r<4;r++){
        const int gm = wave*128 + m*16 + (lane>>4)*4 + r;
        float v = acc[m][n][r] + bv;
        if (EPI & 8) v = gelu_tanh_f(v);
        if (EPI & 1) Cf[(size_t)gm*Nc + ccol0 + col] = v;
        if (EPI & 2) Cb[(size_t)gm*Nc + ccol0 + col] = (bf16_t)v;
        if (EPI & 4) Cb[(size_t)gm*Nc + swz_col(gm, ccol0 + col)] = (bf16_t)v;
      }
    }
  }
}

template<int EPI>
__global__ __launch_bounds__(256,2) void gemm512_kernel(
    const bf16_t* __restrict__ A, const float* __restrict__ W,
    const float* __restrict__ bias,
    float* __restrict__ Cf, bf16_t* __restrict__ Cb, int N, int K)
{
  const int bc  = blockIdx.x * 64;
  const int z   = blockIdx.y;
  const int ktn = (K>>5) / gridDim.y;
  gemm512_body<EPI>(A, W + (size_t)bc*K, bias ? bias + bc : nullptr,
                    Cf ? Cf + (size_t)z*512*N : nullptr, Cb,
                    N, K, z*ktn, ktn, bc);
}

__global__ __launch_bounds__(256,2) void gemm512_qkv_kernel(
    const bf16_t* __restrict__ A,
    const float* __restrict__ W0, const float* __restrict__ W1, const float* __restrict__ W2,
    const float* __restrict__ b0, const float* __restrict__ b1, const float* __restrict__ b2,
    bf16_t* __restrict__ C0, bf16_t* __restrict__ C1, bf16_t* __restrict__ C2)
{
  const int bc = blockIdx.x * 64;
  const int which = bc >> 12;
  const int lc = bc & 4095;
  const float* W    = (which==0) ? W0 : ((which==1) ? W1 : W2);
  const float* bias = (which==0) ? b0 : ((which==1) ? b1 : b2);
  bf16_t* C         = (which==0) ? C0 : ((which==1) ? C1 : C2);
  gemm512_body<2>(A, W + (size_t)lc*4096, bias + lc, nullptr, C, 4096, 4096, 0, 128, lc);
}

// ============ flash attention: grid (4 qblocks, 64 heads), 256 thr ============
__global__ __launch_bounds__(256) void attn_kernel(
    const bf16_t* __restrict__ q, const bf16_t* __restrict__ k,
    const bf16_t* __restrict__ v, bf16_t* __restrict__ ctx)
{
  constexpr int HID = 4096;
  const int qblk = blockIdx.x, head = blockIdx.y;
  const int tid = threadIdx.x, lane = tid & 63, wave = tid >> 6;

  __shared__ __align__(16) bf16_t Ks[128][72];
  __shared__ __align__(16) bf16_t Vt[64][136];
  __shared__ __align__(16) bf16_t Ps[4][32][136];

  bf16x8 qf[2][2];
  const int qrow0 = qblk*128 + wave*32;
  #pragma unroll
  for (int m=0;m<2;m++)
    #pragma unroll
    for (int ks=0;ks<2;ks++)
      qf[m][ks] = *(const bf16x8*)(q + (size_t)(qrow0 + m*16 + (lane&15))*HID + head*64 + ks*32 + (lane>>4)*8);

  f32x4 o[2][4];
  float mrow[2][4], lrow[2][4];
  #pragma unroll
  for (int m=0;m<2;m++){
    #pragma unroll
    for (int n=0;n<4;n++) o[m][n] = zero4();
    #pragma unroll
    for (int r=0;r<4;r++){ mrow[m][r] = -1e30f; lrow[m][r] = 0.f; }
  }

  for (int t=0; t<4; ++t){
    __syncthreads();
    #pragma unroll
    for (int i=0;i<4;i++){
      int s = tid + i*256; int row = s>>3; int c0 = (s&7)*8;
      *(bf16x8*)&Ks[row][c0] = *(const bf16x8*)(k + (size_t)(t*128+row)*HID + head*64 + c0);
    }
    #pragma unroll
    for (int i=0;i<4;i++){
      int s = tid + i*256; int row = s>>3; int c0 = (s&7)*8;
      bf16x8 vv = *(const bf16x8*)(v + (size_t)(t*128+row)*HID + head*64 + c0);
      #pragma unroll
      for (int e=0;e<8;e++) Vt[c0+e][row] = vv[e];
    }
    __syncthreads();

    f32x4 sa[2][8];
    #pragma unroll
    for (int m=0;m<2;m++)
      #pragma unroll
      for (int n=0;n<8;n++) sa[m][n] = zero4();
    #pragma unroll
    for (int ks=0;ks<2;ks++){
      #pragma unroll
      for (int n=0;n<8;n++){
        bf16x8 kf = *(const bf16x8*)&Ks[n*16 + (lane&15)][ks*32 + (lane>>4)*8];
        sa[0][n] = __builtin_amdgcn_mfma_f32_16x16x32_bf16(qf[0][ks], kf, sa[0][n], 0,0,0);
        sa[1][n] = __builtin_amdgcn_mfma_f32_16x16x32_bf16(qf[1][ks], kf, sa[1][n], 0,0,0);
      }
    }

    #pragma unroll
    for (int m=0;m<2;m++){
      float pm[4], rs[4];
      #pragma unroll
      for (int r=0;r<4;r++){
        float mx = sa[m][0][r];
        #pragma unroll
        for (int n=1;n<8;n++) mx = fmaxf(mx, sa[m][n][r]);
        pm[r] = mx * 0.125f;
        #pragma unroll
        for (int off=1; off<16; off<<=1) pm[r] = fmaxf(pm[r], __shfl_xor(pm[r], off));
        float mnew  = fmaxf(mrow[m][r], pm[r]);
        float alpha = __expf(mrow[m][r] - mnew);
        mrow[m][r] = mnew; lrow[m][r] *= alpha;
        #pragma unroll
        for (int n=0;n<4;n++) o[m][n][r] *= alpha;
        rs[r] = 0.f;
      }
      #pragma unroll
      for (int n=0;n<8;n++)
        #pragma unroll
        for (int r=0;r<4;r++){
          float p = __expf(sa[m][n][r]*0.125f - mrow[m][r]);
          rs[r] += p;
          Ps[wave][m*16 + (lane>>4)*4 + r][n*16 + (lane&15)] = (bf16_t)p;
        }
      #pragma unroll
      for (int r=0;r<4;r++){
        #pragma unroll
        for (int off=1; off<16; off<<=1) rs[r] += __shfl_xor(rs[r], off);
        lrow[m][r] += rs[r];
      }
    }

    #pragma unroll
    for (int ksv=0;ksv<4;ksv++){
      bf16x8 pf[2], vf[4];
      #pragma unroll
      for (int m=0;m<2;m++)
        pf[m] = *(const bf16x8*)&Ps[wave][m*16 + (lane&15)][ksv*32 + (lane>>4)*8];
      #pragma unroll
      for (int n=0;n<4;n++)
        vf[n] = *(const bf16x8*)&Vt[n*16 + (lane&15)][ksv*32 + (lane>>4)*8];
      #pragma unroll
      for (int m=0;m<2;m++)
        #pragma unroll
        for (int n=0;n<4;n++)
          o[m][n] = __builtin_amdgcn_mfma_f32_16x16x32_bf16(pf[m], vf[n], o[m][n], 0,0,0);
    }
  }

  #pragma unroll
  for (int m=0;m<2;m++)
    #pragma unroll
    for (int n=0;n<4;n++)
      #pragma unroll
      for (int r=0;r<4;r++){
        const int gm = qrow0 + m*16 + (lane>>4)*4 + r;
        const int gd = head*64 + n*16 + (lane&15);
        ctx[(size_t)gm*HID + swz_col(gm, gd)] = (bf16_t)(o[m][n][r] / lrow[m][r]);
      }
}

// ============ LN over 4096: x = p0+p1+p2+p3 + bias + resid ============
__global__ __launch_bounds__(256) void ln_final_kernel(
    const float* __restrict__ p, const float* __restrict__ resid,
    const float* __restrict__ bias,
    const float* __restrict__ g, const float* __restrict__ b,
    float* __restrict__ yf, bf16_t* __restrict__ yb)
{
  __shared__ float red[4];
  const int row = blockIdx.x, tid = threadIdx.x;
  const size_t base = (size_t)row * 4096;
  const size_t ps = (size_t)512*4096;
  float vals[16];
  float s = 0.f;
  #pragma unroll
  for (int i=0;i<16;i++){
    int c = i*256 + tid;
    float t = p[base+c] + p[ps+base+c] + p[2*ps+base+c] + p[3*ps+base+c]
            + bias[c] + resid[base+c];
    vals[i] = t; s += t;
  }
  #pragma unroll
  for (int off=1; off<64; off<<=1) s += __shfl_xor(s, off);
  if (!(tid&63)) red[tid>>6] = s;
  __syncthreads();
  const float mean = (red[0]+red[1]+red[2]+red[3]) * (1.0f/4096.0f);
  __syncthreads();
  float s2 = 0.f;
  #pragma unroll
  for (int i=0;i<16;i++){ float d = vals[i]-mean; s2 += d*d; }
  #pragma unroll
  for (int off=1; off<64; off<<=1) s2 += __shfl_xor(s2, off);
  if (!(tid&63)) red[tid>>6] = s2;
  __syncthreads();
  const float rstd = rsqrtf((red[0]+red[1]+red[2]+red[3])*(1.0f/4096.0f) + 1e-12f);
  #pragma unroll
  for (int i=0;i<16;i++){
    int c = i*256 + tid;
    float y = (vals[i]-mean)*rstd*g[c] + b[c];
    yf[base+c] = y;
    if (yb) yb[base + swz_col(row, c)] = (bf16_t)y;
  }
}

// ============ embeddings + LN(128) -> bf16 swizzled ============
__global__ __launch_bounds__(128) void embed_ln_kernel(
    const float* __restrict__ we, const float* __restrict__ te, const float* __restrict__ pe,
    const float* __restrict__ g, const float* __restrict__ bb,
    const int* __restrict__ ids, const int* __restrict__ tt, const int* __restrict__ pos,
    bf16_t* __restrict__ out)
{
  __shared__ float red[2];
  const int row = blockIdx.x, tid = threadIdx.x;
  float e = we[(size_t)ids[row]*128 + tid] + te[(size_t)tt[row]*128 + tid] + pe[(size_t)pos[row]*128 + tid];
  float s = e;
  #pragma unroll
  for (int off=1; off<64; off<<=1) s += __shfl_xor(s, off);
  if (!(tid&63)) red[tid>>6] = s;
  __syncthreads();
  const float mean = (red[0]+red[1]) * (1.0f/128.0f);
  __syncthreads();
  float d = e - mean;
  float s2 = d*d;
  #pragma unroll
  for (int off=1; off<64; off<<=1) s2 += __shfl_xor(s2, off);
  if (!(tid&63)) red[tid>>6] = s2;
  __syncthreads();
  const float var = (red[0]+red[1]) * (1.0f/128.0f);
  float y = d * rsqrtf(var + 1e-12f) * g[tid] + bb[tid];
  out[(size_t)row*128 + swz_col(row, tid)] = (bf16_t)y;
}

// ============ launch ============
extern "C" void kernel_launch(void* const* d_in, const int* in_sizes, int n_in,
                              void* d_out, int out_size, void* d_ws, size_t ws_size,
                              hipStream_t stream) {
  const float* we   = (const float*)d_in[0];
  const float* te   = (const float*)d_in[1];
  const float* pe   = (const float*)d_in[2];
  const float* ln0g = (const float*)d_in[3];
  const float* ln0b = (const float*)d_in[4];
  const float* Wp   = (const float*)d_in[5];
  const float* bp   = (const float*)d_in[6];
  const float* Wq   = (const float*)d_in[7];
  const float* bq   = (const float*)d_in[8];
  const float* Wk   = (const float*)d_in[9];
  const float* bk   = (const float*)d_in[10];
  const float* Wv   = (const float*)d_in[11];
  const float* bv   = (const float*)d_in[12];
  const float* Wo   = (const float*)d_in[13];
  const float* bo   = (const float*)d_in[14];
  const float* ln1g = (const float*)d_in[15];
  const float* ln1b = (const float*)d_in[16];
  const float* Wf1  = (const float*)d_in[17];
  const float* bf1  = (const float*)d_in[18];
  const float* Wf2  = (const float*)d_in[19];
  const float* bf2  = (const float*)d_in[20];
  const float* ln2g = (const float*)d_in[21];
  const float* ln2b = (const float*)d_in[22];
  const int* ids = (const int*)d_in[23];
  const int* tt  = (const int*)d_in[24];
  const int* pos = (const int*)d_in[25];
  float* out = (float*)d_out;

  float* ws = (float*)d_ws;
  const size_t M1 = (size_t)1024*1024;
  const size_t MN = 2*M1;                 // 512*4096
  float* hidden_f32 = ws;                 // [0, 2M)
  float* part       = ws + 2*M1;          // [2M, 10M)  4 partials
  float* h1_f32     = ws + 10*M1;         // [10M, 12M)
  bf16_t* b16 = (bf16_t*)(ws + 12*M1);
  bf16_t* qb     = b16;                   // 2M elems
  bf16_t* kb     = b16 + 2*M1;
  bf16_t* vb     = b16 + 4*M1;
  bf16_t* ctxb   = b16 + 6*M1;
  bf16_t* hid_b  = b16 + 8*M1;
  bf16_t* h1_b   = b16 + 10*M1;
  bf16_t* he_b   = b16 + 12*M1;           // 64K elems
  bf16_t* gelu_b = b16;                   // reuse q/k/v/ctx region (8M elems)

  // embeddings + LN0 -> h_e bf16 swizzled
  embed_ln_kernel<<<dim3(512),dim3(128),0,stream>>>(we,te,pe,ln0g,ln0b,ids,tt,pos,he_b);
  // hidden = h_e @ Wp^T + bp : fp32 + bf16swz
  gemm512_kernel<5><<<dim3(64,1),dim3(256),0,stream>>>(he_b, Wp, bp, hidden_f32, hid_b, 4096, 128);
  // q,k,v (bf16 linear)
  gemm512_qkv_kernel<<<dim3(192,1),dim3(256),0,stream>>>(hid_b, Wq,Wk,Wv, bq,bk,bv, qb,kb,vb);
  // attention -> ctx bf16 swizzled
  attn_kernel<<<dim3(4,64),dim3(256),0,stream>>>(qb, kb, vb, ctxb);
  // attn_out partials = ctx @ Wo^T (split-K=4)
  gemm512_kernel<1><<<dim3(64,4),dim3(256),0,stream>>>(ctxb, Wo, nullptr, part, nullptr, 4096, 4096);
  // h1 = LN(sum(part) + bo + hidden)
  ln_final_kernel<<<dim3(512),dim3(256),0,stream>>>(part, hidden_f32, bo, ln1g, ln1b, h1_f32, h1_b);
  // gelu(h1 @ Wf1^T + bf1) -> bf16 swizzled
  gemm512_kernel<12><<<dim3(256,1),dim3(256),0,stream>>>(h1_b, Wf1, bf1, nullptr, gelu_b, 16384, 4096);
  // ff2 partials = gelu @ Wf2^T (split-K=4)
  gemm512_kernel<1><<<dim3(64,4),dim3(256),0,stream>>>(gelu_b, Wf2, nullptr, part, nullptr, 4096, 16384);
  // out = LN(sum(part) + bf2 + h1)
  ln_final_kernel<<<dim3(512),dim3(256),0,stream>>>(part, h1_f32, bf2, ln2g, ln2b, out, nullptr);
}